// Round 5
// baseline (537.634 us; speedup 1.0000x reference)
//
#include <hip/hip_runtime.h>
#include <cstdint>

using u16 = unsigned short;
using u32 = unsigned int;
typedef __attribute__((ext_vector_type(8))) short short8;
typedef __attribute__((ext_vector_type(4))) float f32x4;

__device__ __forceinline__ float bf2f(u16 u) { return __uint_as_float(((u32)u) << 16); }
__device__ __forceinline__ u16 f2bf(float f) {
    u32 u = __float_as_uint(f);
    u32 r = u + 0x7fffu + ((u >> 16) & 1u);   // round-to-nearest-even
    return (u16)(r >> 16);
}

__device__ __forceinline__ void load_lds16(const void* g, void* l) {
    __builtin_amdgcn_global_load_lds((const __attribute__((address_space(1))) void*)g,
                                     (__attribute__((address_space(3))) void*)l, 16, 0, 0);
}

// ---------------- LayerNorm(row of 1024 fp32) -> bf16 ----------------
__global__ __launch_bounds__(256)
void ln_cast_kernel(const float* __restrict__ x, const float* __restrict__ gw,
                    const float* __restrict__ bw, u16* __restrict__ y) {
    const int row = blockIdx.x;
    const int tid = threadIdx.x;
    const float4 v = ((const float4*)(x + (size_t)row * 1024))[tid];
    float s  = v.x + v.y + v.z + v.w;
    float ss = v.x * v.x + v.y * v.y + v.z * v.z + v.w * v.w;
#pragma unroll
    for (int off = 32; off; off >>= 1) {
        s  += __shfl_xor(s, off);
        ss += __shfl_xor(ss, off);
    }
    __shared__ float sm[8];
    const int lane = tid & 63, wid = tid >> 6;
    if (lane == 0) { sm[wid] = s; sm[wid + 4] = ss; }
    __syncthreads();
    s  = sm[0] + sm[1] + sm[2] + sm[3];
    ss = sm[4] + sm[5] + sm[6] + sm[7];
    const float mu   = s * (1.0f / 1024.0f);
    const float var  = ss * (1.0f / 1024.0f) - mu * mu;
    const float rstd = rsqrtf(var + 1e-5f);
    const float4 g4 = ((const float4*)gw)[tid];
    const float4 b4 = ((const float4*)bw)[tid];
    u16 o[4];
    o[0] = f2bf((v.x - mu) * rstd * g4.x + b4.x);
    o[1] = f2bf((v.y - mu) * rstd * g4.y + b4.y);
    o[2] = f2bf((v.z - mu) * rstd * g4.z + b4.z);
    o[3] = f2bf((v.w - mu) * rstd * g4.w + b4.w);
    *(uint2*)(y + (size_t)row * 1024 + tid * 4) = *(uint2*)o;
}

// ---------------- fp32 -> bf16 cast of the 3 weight matrices ----------------
__global__ __launch_bounds__(256)
void cast3_kernel(const float* __restrict__ wa, const float* __restrict__ wb,
                  const float* __restrict__ wc, u16* __restrict__ oa) {
    const int bid = blockIdx.x;
    const int sel = bid >> 10;
    const float* s = (sel == 0) ? wa : (sel == 1) ? wb : wc;
    u16* d = oa + (size_t)sel * 1048576;
    const int i = (bid & 1023) * 256 + threadIdx.x;
    const float4 v = ((const float4*)s)[i];
    u16 o[4] = { f2bf(v.x), f2bf(v.y), f2bf(v.z), f2bf(v.w) };
    *(uint2*)(d + (size_t)i * 4) = *(uint2*)o;
}

// ---------------- GEMM  C = A(MxK) * B(NxK)^T  (both K-contiguous, bf16 in) -----
// BK=64, 128x128 tile, XOR-swizzled LDS (conflict-free; see r2/r3 notes).
// Fragment LDS addresses are per-lane loop-invariant: byte = (row0)*128 +
// swiz*16 + i*2048, with the s=1 phase exactly ^64 bytes (since (fq+4)^x ==
// (fq^x)^4). We materialize 2 base offsets per matrix and let i*1024-element
// deltas fold into ds_read offset immediates -> minimal live VGPRs. A-frags
// are streamed one at a time into their MFMAs (B-frags stay resident) to cut
// peak frag registers 32 -> ~20, targeting arch<=64 VGPR => 4 waves/SIMD.
// MODE 0: bf16 out row-major, +bias              (Q/K projection)
// MODE 1: bf16 out transposed per batch, +bias   (V projection -> vT[b][n][m%2048])
// MODE 2: bf16 out = exp(acc*scale), per batch   (dots -> unnormalized P)
// MODE 3: fp32 out = (P@V) / rowsum(P), per batch (PV + fused softmax denom
//         via ones-vector MFMA on the already-loaded A-frags)
template<int MODE>
__global__ __launch_bounds__(256, (MODE == 3 ? 3 : 4))
void gemm_bt(const u16* __restrict__ A, const u16* __restrict__ B,
             const float* __restrict__ bias, void* __restrict__ Cout,
             const int M, const int N, const int K, const float scale,
             const long sA, const long sB, const long sC)
{
    const int bz = blockIdx.z;
    A += (long)bz * sA;
    B += (long)bz * sB;
    __shared__ __align__(16) u16 As[128 * 64];   // 16 KB
    __shared__ __align__(16) u16 Bs[128 * 64];   // 16 KB
    const int tid  = threadIdx.x;
    const int lane = tid & 63, wid = tid >> 6;
    const int wm = (wid & 1) * 64, wn = (wid >> 1) * 64;
    const int m0 = blockIdx.x * 128, n0 = blockIdx.y * 128;

    // staging: round rd covers rows rd*32..rd*32+31; thread t -> row rd*32+(t>>3),
    // fetches global 16B col-group (t&7)^((t>>3)&7)  (swizzle)
    const int scol = (tid & 7) ^ ((tid >> 3) & 7);
    const u16* ap = A + (long)(m0 + (tid >> 3)) * K + scol * 8;
    const u16* bp = B + (long)(n0 + (tid >> 3)) * K + scol * 8;
    u16* asd = As + wid * 512;   // + rd*2048 per round; HW adds lane*16B
    u16* bsd = Bs + wid * 512;
    const long rs32 = 32L * K;

    f32x4 acc[4][4] = {};
    f32x4 acc_l[4] = {};  // MODE 3 only: row sums of A (P) via ones-MFMA
    const short8 ones8 = {16256, 16256, 16256, 16256, 16256, 16256, 16256, 16256}; // bf16 1.0
    const int fr = lane & 15, fq = lane >> 4;
    const int sw = (fq ^ (fr & 7)) * 8;               // elements
    const int offA0 = (wm + fr) * 64 + sw;            // s=0 base (elements)
    const int offA1 = offA0 ^ 32;                     // s=1 base
    const int offB0 = (wn + fr) * 64 + sw;
    const int offB1 = offB0 ^ 32;

    for (int k0 = 0; k0 < K; k0 += 64) {
#pragma unroll
        for (int rd = 0; rd < 4; rd++) {
            load_lds16(ap + k0 + rd * rs32, asd + rd * 2048);
            load_lds16(bp + k0 + rd * rs32, bsd + rd * 2048);
        }
        __syncthreads();
#pragma unroll
        for (int s = 0; s < 2; s++) {
            const int oa = s ? offA1 : offA0;
            const int ob = s ? offB1 : offB0;
            short8 b0 = *(const short8*)&Bs[ob];
            short8 b1 = *(const short8*)&Bs[ob + 1024];
            short8 b2 = *(const short8*)&Bs[ob + 2048];
            short8 b3 = *(const short8*)&Bs[ob + 3072];
#pragma unroll
            for (int i = 0; i < 4; i++) {
                const short8 a = *(const short8*)&As[oa + i * 1024];
                acc[i][0] = __builtin_amdgcn_mfma_f32_16x16x32_bf16(a, b0, acc[i][0], 0, 0, 0);
                acc[i][1] = __builtin_amdgcn_mfma_f32_16x16x32_bf16(a, b1, acc[i][1], 0, 0, 0);
                acc[i][2] = __builtin_amdgcn_mfma_f32_16x16x32_bf16(a, b2, acc[i][2], 0, 0, 0);
                acc[i][3] = __builtin_amdgcn_mfma_f32_16x16x32_bf16(a, b3, acc[i][3], 0, 0, 0);
                if (MODE == 3)
                    acc_l[i] = __builtin_amdgcn_mfma_f32_16x16x32_bf16(a, ones8, acc_l[i], 0, 0, 0);
            }
        }
        __syncthreads();
    }

    // epilogue: C/D layout col=lane&15, row=(lane>>4)*4+r
    const int cn = lane & 15;
    const int cm = (lane >> 4) * 4;
    float invl[4][4];
    if (MODE == 3) {
#pragma unroll
        for (int i = 0; i < 4; i++)
#pragma unroll
            for (int r = 0; r < 4; r++) invl[i][r] = 1.0f / acc_l[i][r];
    }
#pragma unroll
    for (int i = 0; i < 4; i++) {
        const int gmb = m0 + wm + i * 16 + cm;
#pragma unroll
        for (int j = 0; j < 4; j++) {
            const int gn = n0 + wn + j * 16 + cn;
            const float bv = (MODE <= 1) ? bias[gn] : 0.0f;
            if (MODE == 1) {
                const int batch = gmb >> 11;
                const int jj = gmb & 2047;
                u16 o[4];
#pragma unroll
                for (int r = 0; r < 4; r++) o[r] = f2bf(acc[i][j][r] + bv);
                *(uint2*)((u16*)Cout + ((long)batch * N + gn) * 2048 + jj) = *(uint2*)o;
            } else {
#pragma unroll
                for (int r = 0; r < 4; r++) {
                    const long gm = gmb + r;
                    float v = acc[i][j][r];
                    if (MODE == 0) v += bv;
                    if (MODE == 2) v = __expf(v * scale);
                    if (MODE == 3)
                        ((float*)Cout)[(long)bz * sC + gm * N + gn] = v * invl[i][r];
                    else if (MODE == 2)
                        ((u16*)Cout)[(long)bz * sC + gm * N + gn] = f2bf(v);
                    else
                        ((u16*)Cout)[gm * (long)N + gn] = f2bf(v);
                }
            }
        }
    }
}

extern "C" void kernel_launch(void* const* d_in, const int* in_sizes, int n_in,
                              void* d_out, int out_size, void* d_ws, size_t ws_size,
                              hipStream_t stream) {
    const float* target = (const float*)d_in[0];
    const float* src_k  = (const float*)d_in[1];
    const float* src_v  = (const float*)d_in[2];
    const float* Wq = (const float*)d_in[3];
    const float* bq = (const float*)d_in[4];
    const float* Wk = (const float*)d_in[5];
    const float* bk = (const float*)d_in[6];
    const float* Wv = (const float*)d_in[7];
    const float* bv = (const float*)d_in[8];
    const float* g_t = (const float*)d_in[9];
    const float* b_t = (const float*)d_in[10];
    const float* g_k = (const float*)d_in[11];
    const float* b_k = (const float*)d_in[12];
    const float* g_v = (const float*)d_in[13];
    const float* b_v = (const float*)d_in[14];

    // workspace layout (bytes); peak use ~160 MiB
    char* ws = (char*)d_ws;
    u16* q   = (u16*)(ws + 0);            // 16384x1024 bf16  (33.5 MB)
    u16* kk  = (u16*)(ws + 33554432L);    // 16384x1024 bf16
    u16* vT  = (u16*)(ws + 67108864L);    // 8 x 1024 x 2048 bf16
    u16* ln  = (u16*)(ws + 100663296L);   // 16384x1024 bf16 (reused 3x)
    u16* wqb = (u16*)(ws + 134217728L);   // 3 x 1024x1024 bf16 (contiguous)
    u16* wkb = wqb + 1048576;
    u16* wvb = wkb + 1048576;
    u16* S   = (u16*)(ws + 100663296L);   // 8x2048x2048 bf16 (aliases ln+W, both dead)

    const float scale = 0.03125f;  // 1024^-0.5

    cast3_kernel<<<3072, 256, 0, stream>>>(Wq, Wk, Wv, wqb);

    // Q = LN(target) @ Wq^T + bq
    ln_cast_kernel<<<16384, 256, 0, stream>>>(target, g_t, b_t, ln);
    gemm_bt<0><<<dim3(128, 8, 1), 256, 0, stream>>>(ln, wqb, bq, q,
        16384, 1024, 1024, 1.0f, 0, 0, 0);
    // K = LN(source_k) @ Wk^T + bk
    ln_cast_kernel<<<16384, 256, 0, stream>>>(src_k, g_k, b_k, ln);
    gemm_bt<0><<<dim3(128, 8, 1), 256, 0, stream>>>(ln, wkb, bk, kk,
        16384, 1024, 1024, 1.0f, 0, 0, 0);
    // V = LN(source_v) @ Wv^T + bv, stored transposed per batch: vT[b][d][j]
    ln_cast_kernel<<<16384, 256, 0, stream>>>(src_v, g_v, b_v, ln);
    gemm_bt<1><<<dim3(128, 8, 1), 256, 0, stream>>>(ln, wvb, bv, vT,
        16384, 1024, 1024, 1.0f, 0, 0, 0);

    // P[b] = exp((q[b] @ k[b]^T) * scale)  -> unnormalized bf16 probs
    gemm_bt<2><<<dim3(16, 16, 8), 256, 0, stream>>>(q, kk, nullptr, S,
        2048, 2048, 1024, scale, 2048L * 1024, 2048L * 1024, 2048L * 2048);

    // out[b] = (P[b] @ vT[b]^T) / rowsum(P[b])  -> fp32 (softmax denom fused)
    gemm_bt<3><<<dim3(16, 8, 8), 256, 0, stream>>>(S, vT, nullptr, d_out,
        2048, 1024, 2048, 1.0f, 2048L * 2048, 1024L * 2048, 2048L * 1024);
}

// Round 6
// 523.251 us; speedup vs baseline: 1.0275x; 1.0275x over previous
//
#include <hip/hip_runtime.h>
#include <cstdint>

using u16 = unsigned short;
using u32 = unsigned int;
typedef __attribute__((ext_vector_type(8))) short short8;
typedef __attribute__((ext_vector_type(4))) float f32x4;

__device__ __forceinline__ float bf2f(u16 u) { return __uint_as_float(((u32)u) << 16); }
__device__ __forceinline__ u16 f2bf(float f) {
    u32 u = __float_as_uint(f);
    u32 r = u + 0x7fffu + ((u >> 16) & 1u);   // round-to-nearest-even
    return (u16)(r >> 16);
}

__device__ __forceinline__ void load_lds16(const void* g, void* l) {
    __builtin_amdgcn_global_load_lds((const __attribute__((address_space(1))) void*)g,
                                     (__attribute__((address_space(3))) void*)l, 16, 0, 0);
}

// ---------------- LayerNorm(row of 1024 fp32) -> bf16 ----------------
__global__ __launch_bounds__(256)
void ln_cast_kernel(const float* __restrict__ x, const float* __restrict__ gw,
                    const float* __restrict__ bw, u16* __restrict__ y) {
    const int row = blockIdx.x;
    const int tid = threadIdx.x;
    const float4 v = ((const float4*)(x + (size_t)row * 1024))[tid];
    float s  = v.x + v.y + v.z + v.w;
    float ss = v.x * v.x + v.y * v.y + v.z * v.z + v.w * v.w;
#pragma unroll
    for (int off = 32; off; off >>= 1) {
        s  += __shfl_xor(s, off);
        ss += __shfl_xor(ss, off);
    }
    __shared__ float sm[8];
    const int lane = tid & 63, wid = tid >> 6;
    if (lane == 0) { sm[wid] = s; sm[wid + 4] = ss; }
    __syncthreads();
    s  = sm[0] + sm[1] + sm[2] + sm[3];
    ss = sm[4] + sm[5] + sm[6] + sm[7];
    const float mu   = s * (1.0f / 1024.0f);
    const float var  = ss * (1.0f / 1024.0f) - mu * mu;
    const float rstd = rsqrtf(var + 1e-5f);
    const float4 g4 = ((const float4*)gw)[tid];
    const float4 b4 = ((const float4*)bw)[tid];
    u16 o[4];
    o[0] = f2bf((v.x - mu) * rstd * g4.x + b4.x);
    o[1] = f2bf((v.y - mu) * rstd * g4.y + b4.y);
    o[2] = f2bf((v.z - mu) * rstd * g4.z + b4.z);
    o[3] = f2bf((v.w - mu) * rstd * g4.w + b4.w);
    *(uint2*)(y + (size_t)row * 1024 + tid * 4) = *(uint2*)o;
}

// ---------------- fp32 -> bf16 cast of the 3 weight matrices ----------------
__global__ __launch_bounds__(256)
void cast3_kernel(const float* __restrict__ wa, const float* __restrict__ wb,
                  const float* __restrict__ wc, u16* __restrict__ oa) {
    const int bid = blockIdx.x;
    const int sel = bid >> 10;
    const float* s = (sel == 0) ? wa : (sel == 1) ? wb : wc;
    u16* d = oa + (size_t)sel * 1048576;
    const int i = (bid & 1023) * 256 + threadIdx.x;
    const float4 v = ((const float4*)s)[i];
    u16 o[4] = { f2bf(v.x), f2bf(v.y), f2bf(v.z), f2bf(v.w) };
    *(uint2*)(d + (size_t)i * 4) = *(uint2*)o;
}

// ---------------- GEMM  C = A(MxK) * B(NxK)^T  (both K-contiguous, bf16 in) -----
// BK=64, 128x128 tile, XOR-swizzled LDS (conflict-free; see r2/r3 notes).
// Loop-invariant fragment addresses + streamed A-frags (r5): VALUBusy 42->19%.
// MODE>=2 use a 1-D grid with XCD-aware decode: b = id&7 (one batch per XCD,
// XCD = linear block id % 8 on MI355X), m = (id>>3)&15, n = id>>7. This makes
// all q/k (resp. P/vT) reads XCD-local -> k-tiles L2-hit instead of HBM-miss,
// shrinking the vmcnt(0) barrier-drain latency (r5: FETCH 164MB vs 64 ideal).
// MODE 0: bf16 out row-major, +bias              (Q/K projection)
// MODE 1: bf16 out transposed per batch, +bias   (V projection -> vT[b][n][m%2048])
// MODE 2: bf16 out = exp(acc*scale), per batch   (dots -> unnormalized P)
// MODE 3: fp32 out = (P@V) / rowsum(P), per batch (PV + fused softmax denom
//         via ones-vector MFMA on the already-loaded A-frags)
template<int MODE>
__global__ __launch_bounds__(256, (MODE == 3 ? 3 : 4))
void gemm_bt(const u16* __restrict__ A, const u16* __restrict__ B,
             const float* __restrict__ bias, void* __restrict__ Cout,
             const int M, const int N, const int K, const float scale,
             const long sA, const long sB, const long sC)
{
    int bz, m0, n0;
    if (MODE >= 2) {
        const int id = blockIdx.x;
        bz = id & 7;
        m0 = ((id >> 3) & 15) * 128;
        n0 = (id >> 7) * 128;
    } else {
        bz = 0;
        m0 = blockIdx.x * 128;
        n0 = blockIdx.y * 128;
    }
    A += (long)bz * sA;
    B += (long)bz * sB;
    __shared__ __align__(16) u16 As[128 * 64];   // 16 KB
    __shared__ __align__(16) u16 Bs[128 * 64];   // 16 KB
    const int tid  = threadIdx.x;
    const int lane = tid & 63, wid = tid >> 6;
    const int wm = (wid & 1) * 64, wn = (wid >> 1) * 64;

    // staging: round rd covers rows rd*32..rd*32+31; thread t -> row rd*32+(t>>3),
    // fetches global 16B col-group (t&7)^((t>>3)&7)  (swizzle)
    const int scol = (tid & 7) ^ ((tid >> 3) & 7);
    const u16* ap = A + (long)(m0 + (tid >> 3)) * K + scol * 8;
    const u16* bp = B + (long)(n0 + (tid >> 3)) * K + scol * 8;
    u16* asd = As + wid * 512;   // + rd*2048 per round; HW adds lane*16B
    u16* bsd = Bs + wid * 512;
    const long rs32 = 32L * K;

    f32x4 acc[4][4] = {};
    f32x4 acc_l[4] = {};  // MODE 3 only: row sums of A (P) via ones-MFMA
    const short8 ones8 = {16256, 16256, 16256, 16256, 16256, 16256, 16256, 16256}; // bf16 1.0
    const int fr = lane & 15, fq = lane >> 4;
    const int sw = (fq ^ (fr & 7)) * 8;               // elements
    const int offA0 = (wm + fr) * 64 + sw;            // s=0 base (elements)
    const int offA1 = offA0 ^ 32;                     // s=1 base
    const int offB0 = (wn + fr) * 64 + sw;
    const int offB1 = offB0 ^ 32;

    for (int k0 = 0; k0 < K; k0 += 64) {
#pragma unroll
        for (int rd = 0; rd < 4; rd++) {
            load_lds16(ap + k0 + rd * rs32, asd + rd * 2048);
            load_lds16(bp + k0 + rd * rs32, bsd + rd * 2048);
        }
        __syncthreads();
#pragma unroll
        for (int s = 0; s < 2; s++) {
            const int oa = s ? offA1 : offA0;
            const int ob = s ? offB1 : offB0;
            short8 b0 = *(const short8*)&Bs[ob];
            short8 b1 = *(const short8*)&Bs[ob + 1024];
            short8 b2 = *(const short8*)&Bs[ob + 2048];
            short8 b3 = *(const short8*)&Bs[ob + 3072];
#pragma unroll
            for (int i = 0; i < 4; i++) {
                const short8 a = *(const short8*)&As[oa + i * 1024];
                acc[i][0] = __builtin_amdgcn_mfma_f32_16x16x32_bf16(a, b0, acc[i][0], 0, 0, 0);
                acc[i][1] = __builtin_amdgcn_mfma_f32_16x16x32_bf16(a, b1, acc[i][1], 0, 0, 0);
                acc[i][2] = __builtin_amdgcn_mfma_f32_16x16x32_bf16(a, b2, acc[i][2], 0, 0, 0);
                acc[i][3] = __builtin_amdgcn_mfma_f32_16x16x32_bf16(a, b3, acc[i][3], 0, 0, 0);
                if (MODE == 3)
                    acc_l[i] = __builtin_amdgcn_mfma_f32_16x16x32_bf16(a, ones8, acc_l[i], 0, 0, 0);
            }
        }
        __syncthreads();
    }

    // epilogue: C/D layout col=lane&15, row=(lane>>4)*4+r
    const int cn = lane & 15;
    const int cm = (lane >> 4) * 4;
    float invl[4][4];
    if (MODE == 3) {
#pragma unroll
        for (int i = 0; i < 4; i++)
#pragma unroll
            for (int r = 0; r < 4; r++) invl[i][r] = 1.0f / acc_l[i][r];
    }
#pragma unroll
    for (int i = 0; i < 4; i++) {
        const int gmb = m0 + wm + i * 16 + cm;
#pragma unroll
        for (int j = 0; j < 4; j++) {
            const int gn = n0 + wn + j * 16 + cn;
            const float bv = (MODE <= 1) ? bias[gn] : 0.0f;
            if (MODE == 1) {
                const int batch = gmb >> 11;
                const int jj = gmb & 2047;
                u16 o[4];
#pragma unroll
                for (int r = 0; r < 4; r++) o[r] = f2bf(acc[i][j][r] + bv);
                *(uint2*)((u16*)Cout + ((long)batch * N + gn) * 2048 + jj) = *(uint2*)o;
            } else {
#pragma unroll
                for (int r = 0; r < 4; r++) {
                    const long gm = gmb + r;
                    float v = acc[i][j][r];
                    if (MODE == 0) v += bv;
                    if (MODE == 2) v = __expf(v * scale);
                    if (MODE == 3)
                        ((float*)Cout)[(long)bz * sC + gm * N + gn] = v * invl[i][r];
                    else if (MODE == 2)
                        ((u16*)Cout)[(long)bz * sC + gm * N + gn] = f2bf(v);
                    else
                        ((u16*)Cout)[gm * (long)N + gn] = f2bf(v);
                }
            }
        }
    }
}

extern "C" void kernel_launch(void* const* d_in, const int* in_sizes, int n_in,
                              void* d_out, int out_size, void* d_ws, size_t ws_size,
                              hipStream_t stream) {
    const float* target = (const float*)d_in[0];
    const float* src_k  = (const float*)d_in[1];
    const float* src_v  = (const float*)d_in[2];
    const float* Wq = (const float*)d_in[3];
    const float* bq = (const float*)d_in[4];
    const float* Wk = (const float*)d_in[5];
    const float* bk = (const float*)d_in[6];
    const float* Wv = (const float*)d_in[7];
    const float* bv = (const float*)d_in[8];
    const float* g_t = (const float*)d_in[9];
    const float* b_t = (const float*)d_in[10];
    const float* g_k = (const float*)d_in[11];
    const float* b_k = (const float*)d_in[12];
    const float* g_v = (const float*)d_in[13];
    const float* b_v = (const float*)d_in[14];

    // workspace layout (bytes); peak use ~160 MiB
    char* ws = (char*)d_ws;
    u16* q   = (u16*)(ws + 0);            // 16384x1024 bf16  (33.5 MB)
    u16* kk  = (u16*)(ws + 33554432L);    // 16384x1024 bf16
    u16* vT  = (u16*)(ws + 67108864L);    // 8 x 1024 x 2048 bf16
    u16* ln  = (u16*)(ws + 100663296L);   // 16384x1024 bf16 (reused 3x)
    u16* wqb = (u16*)(ws + 134217728L);   // 3 x 1024x1024 bf16 (contiguous)
    u16* wkb = wqb + 1048576;
    u16* wvb = wkb + 1048576;
    u16* S   = (u16*)(ws + 100663296L);   // 8x2048x2048 bf16 (aliases ln+W, both dead)

    const float scale = 0.03125f;  // 1024^-0.5

    cast3_kernel<<<3072, 256, 0, stream>>>(Wq, Wk, Wv, wqb);

    // Q = LN(target) @ Wq^T + bq
    ln_cast_kernel<<<16384, 256, 0, stream>>>(target, g_t, b_t, ln);
    gemm_bt<0><<<dim3(128, 8, 1), 256, 0, stream>>>(ln, wqb, bq, q,
        16384, 1024, 1024, 1.0f, 0, 0, 0);
    // K = LN(source_k) @ Wk^T + bk
    ln_cast_kernel<<<16384, 256, 0, stream>>>(src_k, g_k, b_k, ln);
    gemm_bt<0><<<dim3(128, 8, 1), 256, 0, stream>>>(ln, wkb, bk, kk,
        16384, 1024, 1024, 1.0f, 0, 0, 0);
    // V = LN(source_v) @ Wv^T + bv, stored transposed per batch: vT[b][d][j]
    ln_cast_kernel<<<16384, 256, 0, stream>>>(src_v, g_v, b_v, ln);
    gemm_bt<1><<<dim3(128, 8, 1), 256, 0, stream>>>(ln, wvb, bv, vT,
        16384, 1024, 1024, 1.0f, 0, 0, 0);

    // P[b] = exp((q[b] @ k[b]^T) * scale) -> unnormalized bf16 probs
    // 1-D grid, XCD-aware decode: batch = id&7 (one batch per XCD)
    gemm_bt<2><<<2048, 256, 0, stream>>>(q, kk, nullptr, S,
        2048, 2048, 1024, scale, 2048L * 1024, 2048L * 1024, 2048L * 2048);

    // out[b] = (P[b] @ vT[b]^T) / rowsum(P[b]) -> fp32 (softmax denom fused)
    gemm_bt<3><<<1024, 256, 0, stream>>>(S, vT, nullptr, d_out,
        2048, 1024, 2048, 1.0f, 2048L * 2048, 1024L * 2048, 2048L * 1024);
}

// Round 7
// 495.561 us; speedup vs baseline: 1.0849x; 1.0559x over previous
//
#include <hip/hip_runtime.h>
#include <cstdint>

using u16 = unsigned short;
using u32 = unsigned int;
typedef __attribute__((ext_vector_type(8))) short short8;
typedef __attribute__((ext_vector_type(4))) float f32x4;

__device__ __forceinline__ float bf2f(u16 u) { return __uint_as_float(((u32)u) << 16); }
__device__ __forceinline__ u16 f2bf(float f) {
    u32 u = __float_as_uint(f);
    u32 r = u + 0x7fffu + ((u >> 16) & 1u);   // round-to-nearest-even
    return (u16)(r >> 16);
}

__device__ __forceinline__ void load_lds16(const void* g, void* l) {
    __builtin_amdgcn_global_load_lds((const __attribute__((address_space(1))) void*)g,
                                     (__attribute__((address_space(3))) void*)l, 16, 0, 0);
}

// ---------------- LayerNorm row body (1024 fp32 -> bf16) ----------------
__device__ __forceinline__ void ln_row(const float* __restrict__ x,
                                       const float* __restrict__ gw,
                                       const float* __restrict__ bw,
                                       u16* __restrict__ y, int row) {
    const int tid = threadIdx.x;
    const float4 v = ((const float4*)(x + (size_t)row * 1024))[tid];
    float s  = v.x + v.y + v.z + v.w;
    float ss = v.x * v.x + v.y * v.y + v.z * v.z + v.w * v.w;
#pragma unroll
    for (int off = 32; off; off >>= 1) {
        s  += __shfl_xor(s, off);
        ss += __shfl_xor(ss, off);
    }
    __shared__ float sm[8];
    const int lane = tid & 63, wid = tid >> 6;
    if (lane == 0) { sm[wid] = s; sm[wid + 4] = ss; }
    __syncthreads();
    s  = sm[0] + sm[1] + sm[2] + sm[3];
    ss = sm[4] + sm[5] + sm[6] + sm[7];
    const float mu   = s * (1.0f / 1024.0f);
    const float var  = ss * (1.0f / 1024.0f) - mu * mu;
    const float rstd = rsqrtf(var + 1e-5f);
    const float4 g4 = ((const float4*)gw)[tid];
    const float4 b4 = ((const float4*)bw)[tid];
    u16 o[4];
    o[0] = f2bf((v.x - mu) * rstd * g4.x + b4.x);
    o[1] = f2bf((v.y - mu) * rstd * g4.y + b4.y);
    o[2] = f2bf((v.z - mu) * rstd * g4.z + b4.z);
    o[3] = f2bf((v.w - mu) * rstd * g4.w + b4.w);
    *(uint2*)(y + (size_t)row * 1024 + tid * 4) = *(uint2*)o;
}

__global__ __launch_bounds__(256)
void ln_cast_kernel(const float* __restrict__ x, const float* __restrict__ gw,
                    const float* __restrict__ bw, u16* __restrict__ y) {
    ln_row(x, gw, bw, y, blockIdx.x);
}

// merged: all 3 layernorms in one dispatch (sel = bid>>14)
__global__ __launch_bounds__(256)
void ln3_kernel(const float* __restrict__ x0, const float* __restrict__ x1,
                const float* __restrict__ x2,
                const float* __restrict__ g0, const float* __restrict__ g1,
                const float* __restrict__ g2,
                const float* __restrict__ b0, const float* __restrict__ b1,
                const float* __restrict__ b2, u16* __restrict__ y) {
    const int bid = blockIdx.x;
    const int sel = bid >> 14;
    const int row = bid & 16383;
    const float* x  = (sel == 0) ? x0 : (sel == 1) ? x1 : x2;
    const float* gw = (sel == 0) ? g0 : (sel == 1) ? g1 : g2;
    const float* bw = (sel == 0) ? b0 : (sel == 1) ? b1 : b2;
    ln_row(x, gw, bw, y + ((size_t)sel << 24), row);
}

// ---------------- fp32 -> bf16 cast of the 3 weight matrices ----------------
__global__ __launch_bounds__(256)
void cast3_kernel(const float* __restrict__ wa, const float* __restrict__ wb,
                  const float* __restrict__ wc, u16* __restrict__ oa) {
    const int bid = blockIdx.x;
    const int sel = bid >> 10;
    const float* s = (sel == 0) ? wa : (sel == 1) ? wb : wc;
    u16* d = oa + (size_t)sel * 1048576;
    const int i = (bid & 1023) * 256 + threadIdx.x;
    const float4 v = ((const float4*)s)[i];
    u16 o[4] = { f2bf(v.x), f2bf(v.y), f2bf(v.z), f2bf(v.w) };
    *(uint2*)(d + (size_t)i * 4) = *(uint2*)o;
}

// ---------------- GEMM  C = A(MxK) * B(NxK)^T  (both K-contiguous, bf16 in) -----
// BK=64, 128x128 tile, XOR-swizzled LDS (conflict-free; r2/r3), loop-invariant
// fragment addresses + streamed A-frags (r5), XCD-aware decode for MODE 2/3 (r6).
// MODE 0: bf16 out row-major, +bias              (single projection, fallback)
// MODE 1: bf16 out transposed per batch, +bias   (V projection, fallback)
// MODE 2: bf16 out = exp(acc*scale), per batch   (dots -> unnormalized P)
// MODE 3: fp32 out = (P@V) / rowsum(P), per batch (PV + fused softmax denom)
// MODE 4: merged QKV projections in ONE dispatch, grid(128,8,3): z=blockIdx.z
//         selects {A-slab, W, bias, epilogue}; z<2 row-major into Cout+z*16M,
//         z=2 transposed into Cout2 (vT). 3072 uniform blocks = exactly 4 full
//         residency rounds at 3 blocks/CU -> kills the 33%-per-dispatch tail
//         waste of three 1024-block dispatches (r6 theory).
template<int MODE>
__global__ __launch_bounds__(256, (MODE == 3 ? 3 : 4))
void gemm_bt(const u16* __restrict__ A, const u16* __restrict__ B,
             const float* __restrict__ bias0, const float* __restrict__ bias1,
             const float* __restrict__ bias2,
             void* __restrict__ Cout, void* __restrict__ Cout2,
             const int M, const int N, const int K, const float scale,
             const long sA, const long sB, const long sC)
{
    int bz, m0, n0;
    if (MODE == 2 || MODE == 3) {
        const int id = blockIdx.x;
        bz = id & 7;                      // one batch per XCD
        m0 = ((id >> 3) & 15) * 128;
        n0 = (id >> 7) * 128;
    } else {
        bz = (MODE == 4) ? blockIdx.z : 0;
        m0 = blockIdx.x * 128;
        n0 = blockIdx.y * 128;
    }
    A += (long)bz * sA;
    B += (long)bz * sB;
    const float* bias = (MODE == 4) ? (bz == 0 ? bias0 : bz == 1 ? bias1 : bias2)
                                    : bias0;
    __shared__ __align__(16) u16 As[128 * 64];   // 16 KB
    __shared__ __align__(16) u16 Bs[128 * 64];   // 16 KB
    const int tid  = threadIdx.x;
    const int lane = tid & 63, wid = tid >> 6;
    const int wm = (wid & 1) * 64, wn = (wid >> 1) * 64;

    // staging: round rd covers rows rd*32..rd*32+31; thread t -> row rd*32+(t>>3),
    // fetches global 16B col-group (t&7)^((t>>3)&7)  (swizzle)
    const int scol = (tid & 7) ^ ((tid >> 3) & 7);
    const u16* ap = A + (long)(m0 + (tid >> 3)) * K + scol * 8;
    const u16* bp = B + (long)(n0 + (tid >> 3)) * K + scol * 8;
    u16* asd = As + wid * 512;   // + rd*2048 per round; HW adds lane*16B
    u16* bsd = Bs + wid * 512;
    const long rs32 = 32L * K;

    f32x4 acc[4][4] = {};
    f32x4 acc_l[4] = {};  // MODE 3 only: row sums of A (P) via ones-MFMA
    const short8 ones8 = {16256, 16256, 16256, 16256, 16256, 16256, 16256, 16256}; // bf16 1.0
    const int fr = lane & 15, fq = lane >> 4;
    const int sw = (fq ^ (fr & 7)) * 8;               // elements
    const int offA0 = (wm + fr) * 64 + sw;            // s=0 base (elements)
    const int offA1 = offA0 ^ 32;                     // s=1 base
    const int offB0 = (wn + fr) * 64 + sw;
    const int offB1 = offB0 ^ 32;

    for (int k0 = 0; k0 < K; k0 += 64) {
#pragma unroll
        for (int rd = 0; rd < 4; rd++) {
            load_lds16(ap + k0 + rd * rs32, asd + rd * 2048);
            load_lds16(bp + k0 + rd * rs32, bsd + rd * 2048);
        }
        __syncthreads();
#pragma unroll
        for (int s = 0; s < 2; s++) {
            const int oa = s ? offA1 : offA0;
            const int ob = s ? offB1 : offB0;
            short8 b0 = *(const short8*)&Bs[ob];
            short8 b1 = *(const short8*)&Bs[ob + 1024];
            short8 b2 = *(const short8*)&Bs[ob + 2048];
            short8 b3 = *(const short8*)&Bs[ob + 3072];
#pragma unroll
            for (int i = 0; i < 4; i++) {
                const short8 a = *(const short8*)&As[oa + i * 1024];
                acc[i][0] = __builtin_amdgcn_mfma_f32_16x16x32_bf16(a, b0, acc[i][0], 0, 0, 0);
                acc[i][1] = __builtin_amdgcn_mfma_f32_16x16x32_bf16(a, b1, acc[i][1], 0, 0, 0);
                acc[i][2] = __builtin_amdgcn_mfma_f32_16x16x32_bf16(a, b2, acc[i][2], 0, 0, 0);
                acc[i][3] = __builtin_amdgcn_mfma_f32_16x16x32_bf16(a, b3, acc[i][3], 0, 0, 0);
                if (MODE == 3)
                    acc_l[i] = __builtin_amdgcn_mfma_f32_16x16x32_bf16(a, ones8, acc_l[i], 0, 0, 0);
            }
        }
        __syncthreads();
    }

    // epilogue: C/D layout col=lane&15, row=(lane>>4)*4+r
    const int cn = lane & 15;
    const int cm = (lane >> 4) * 4;
    float invl[4][4];
    if (MODE == 3) {
#pragma unroll
        for (int i = 0; i < 4; i++)
#pragma unroll
            for (int r = 0; r < 4; r++) invl[i][r] = 1.0f / acc_l[i][r];
    }
#pragma unroll
    for (int i = 0; i < 4; i++) {
        const int gmb = m0 + wm + i * 16 + cm;
#pragma unroll
        for (int j = 0; j < 4; j++) {
            const int gn = n0 + wn + j * 16 + cn;
            const float bv = (MODE <= 1 || MODE == 4) ? bias[gn] : 0.0f;
            if (MODE == 1 || (MODE == 4 && bz == 2)) {
                // transposed bf16 store: vT[b][gn][gmb%2048]
                u16* dst = (MODE == 4) ? (u16*)Cout2 : (u16*)Cout;
                const int batch = gmb >> 11;
                const int jj = gmb & 2047;
                u16 o[4];
#pragma unroll
                for (int r = 0; r < 4; r++) o[r] = f2bf(acc[i][j][r] + bv);
                *(uint2*)(dst + ((long)batch * N + gn) * 2048 + jj) = *(uint2*)o;
            } else if (MODE == 0 || MODE == 4) {
                u16* dst = (u16*)Cout + ((MODE == 4) ? (long)bz * 16777216 : 0);
#pragma unroll
                for (int r = 0; r < 4; r++)
                    dst[(long)(gmb + r) * N + gn] = f2bf(acc[i][j][r] + bv);
            } else {
#pragma unroll
                for (int r = 0; r < 4; r++) {
                    const long gm = gmb + r;
                    float v = acc[i][j][r];
                    if (MODE == 2) v = __expf(v * scale);
                    if (MODE == 3)
                        ((float*)Cout)[(long)bz * sC + gm * N + gn] = v * invl[i][r];
                    else
                        ((u16*)Cout)[(long)bz * sC + gm * N + gn] = f2bf(v);
                }
            }
        }
    }
}

extern "C" void kernel_launch(void* const* d_in, const int* in_sizes, int n_in,
                              void* d_out, int out_size, void* d_ws, size_t ws_size,
                              hipStream_t stream) {
    const float* target = (const float*)d_in[0];
    const float* src_k  = (const float*)d_in[1];
    const float* src_v  = (const float*)d_in[2];
    const float* Wq = (const float*)d_in[3];
    const float* bq = (const float*)d_in[4];
    const float* Wk = (const float*)d_in[5];
    const float* bk = (const float*)d_in[6];
    const float* Wv = (const float*)d_in[7];
    const float* bv = (const float*)d_in[8];
    const float* g_t = (const float*)d_in[9];
    const float* b_t = (const float*)d_in[10];
    const float* g_k = (const float*)d_in[11];
    const float* b_k = (const float*)d_in[12];
    const float* g_v = (const float*)d_in[13];
    const float* b_v = (const float*)d_in[14];

    char* ws = (char*)d_ws;
    const float scale = 0.03125f;  // 1024^-0.5
    const size_t MB = 1048576;

    if (ws_size >= 198 * MB) {
        // merged path: peak 198 MB
        u16* q   = (u16*)(ws + 0);            // 16384x1024 bf16 (q,kk contiguous)
        u16* kk  = (u16*)(ws + 32 * MB);
        u16* vT  = (u16*)(ws + 64 * MB);      // 8 x 1024 x 2048 bf16
        u16* ln3 = (u16*)(ws + 96 * MB);      // 3 x 16384x1024 bf16 (dead after proj)
        u16* wqb = (u16*)(ws + 192 * MB);     // 3 x 1024x1024 bf16
        u16* S   = (u16*)(ws + 96 * MB);      // 8x2048x2048 bf16 (aliases ln3)

        cast3_kernel<<<3072, 256, 0, stream>>>(Wq, Wk, Wv, wqb);
        ln3_kernel<<<49152, 256, 0, stream>>>(target, src_k, src_v,
                                              g_t, g_k, g_v, b_t, b_k, b_v, ln3);
        // Q/K/V projections in one dispatch (z = which projection)
        gemm_bt<4><<<dim3(128, 8, 3), 256, 0, stream>>>(ln3, wqb, bq, bk, bv,
            q, vT, 16384, 1024, 1024, 1.0f, 16777216L, 1048576L, 0);
        // P[b] = exp((q[b] @ k[b]^T) * scale)
        gemm_bt<2><<<2048, 256, 0, stream>>>(q, kk, nullptr, nullptr, nullptr, S, nullptr,
            2048, 2048, 1024, scale, 2048L * 1024, 2048L * 1024, 2048L * 2048);
        // out[b] = (P[b] @ vT[b]^T) / rowsum(P[b])
        gemm_bt<3><<<1024, 256, 0, stream>>>(S, vT, nullptr, nullptr, nullptr, d_out, nullptr,
            2048, 1024, 2048, 1.0f, 2048L * 2048, 1024L * 2048, 2048L * 1024);
    } else {
        // fallback (r6) path: peak ~140.5 MB
        u16* q   = (u16*)(ws + 0);
        u16* kk  = (u16*)(ws + 32 * MB);
        u16* vT  = (u16*)(ws + 64 * MB);
        u16* ln  = (u16*)(ws + 96 * MB);
        u16* wqb = (u16*)(ws + 128 * MB);
        u16* wkb = wqb + 1048576;
        u16* wvb = wkb + 1048576;
        u16* S   = (u16*)(ws + 96 * MB);

        cast3_kernel<<<3072, 256, 0, stream>>>(Wq, Wk, Wv, wqb);
        ln_cast_kernel<<<16384, 256, 0, stream>>>(target, g_t, b_t, ln);
        gemm_bt<0><<<dim3(128, 8, 1), 256, 0, stream>>>(ln, wqb, bq, nullptr, nullptr,
            q, nullptr, 16384, 1024, 1024, 1.0f, 0, 0, 0);
        ln_cast_kernel<<<16384, 256, 0, stream>>>(src_k, g_k, b_k, ln);
        gemm_bt<0><<<dim3(128, 8, 1), 256, 0, stream>>>(ln, wkb, bk, nullptr, nullptr,
            kk, nullptr, 16384, 1024, 1024, 1.0f, 0, 0, 0);
        ln_cast_kernel<<<16384, 256, 0, stream>>>(src_v, g_v, b_v, ln);
        gemm_bt<1><<<dim3(128, 8, 1), 256, 0, stream>>>(ln, wvb, bv, nullptr, nullptr,
            vT, nullptr, 16384, 1024, 1024, 1.0f, 0, 0, 0);
        gemm_bt<2><<<2048, 256, 0, stream>>>(q, kk, nullptr, nullptr, nullptr, S, nullptr,
            2048, 2048, 1024, scale, 2048L * 1024, 2048L * 1024, 2048L * 2048);
        gemm_bt<3><<<1024, 256, 0, stream>>>(S, vT, nullptr, nullptr, nullptr, d_out, nullptr,
            2048, 1024, 2048, 1.0f, 2048L * 2048, 1024L * 2048, 2048L * 1024);
    }
}